// Round 7
// baseline (5295.741 us; speedup 1.0000x reference)
//
#include <hip/hip_runtime.h>
#include <hip/hip_fp16.h>
#include <stdint.h>

#define NUM_USERS 200000
#define NUM_ITEMS 100000
#define NN (NUM_USERS + NUM_ITEMS)   // 300000
#define D 32
#define NE 9600000
#define TOTAL (NN * D)               // 9,600,000 elements

#define RPB2 128                     // rows per fine bucket
#define B2 ((NN + RPB2 - 1) / RPB2)  // 2344 fine buckets
#define LP 33                        // padded LDS row stride (bank spread)

#define CSH 12                       // coarse bucket = row >> 12 (4096 rows)
#define NC ((NN + (1 << CSH) - 1) >> CSH)   // 74 coarse buckets
#define FPC 32                       // fine buckets per coarse (4096/128)
#define BPC 9                        // fine-pass blocks per coarse region

#define TPB_A 1024                   // partition block size
#define EPT 16                       // edges per thread in partition
#define EPB_A (TPB_A * EPT)          // 16384 edges per block

#define TPB_H 1024                   // bucket-hist block size
#define EPT_H 32
#define EPB_H (TPB_H * EPT_H)        // 32768 edges per block
#define NB_H ((NE + EPB_H - 1) / EPB_H)  // 293 blocks

// ---------------------------------------------------------------------------
// init: x0h = fp16 copy of concat(user_w, item_w).
__global__ __launch_bounds__(256) void init_x0(
    const float4* __restrict__ user_w, const float4* __restrict__ item_w,
    ushort4* __restrict__ x0h) {
    int i = blockIdx.x * 256 + threadIdx.x;
    const int total4 = TOTAL / 4;
    const int ub4 = (NUM_USERS * D) / 4;
    if (i < total4) {
        float4 v = (i < ub4) ? user_w[i] : item_w[i - ub4];
        ushort4 h;
        h.x = __half_as_ushort(__float2half(v.x));
        h.y = __half_as_ushort(__float2half(v.y));
        h.z = __half_as_ushort(__float2half(v.z));
        h.w = __half_as_ushort(__float2half(v.w));
        x0h[i] = h;
    }
}

// ---------------------------------------------------------------------------
// Fine-bucket degree histogram, LDS-privatized.
__global__ __launch_bounds__(TPB_H) void bucket_hist(
    const int4* __restrict__ rows4, int* __restrict__ bcounts) {
    __shared__ int hist[B2];                         // 9376 B
    int tid = threadIdx.x;
    for (int i = tid; i < B2; i += TPB_H) hist[i] = 0;
    __syncthreads();
    int base4 = blockIdx.x * (EPB_H / 4);
    #pragma unroll
    for (int k = 0; k < EPT_H / 4; ++k) {
        int i4 = base4 + k * TPB_H + tid;
        if (i4 < NE / 4) {
            int4 r = rows4[i4];
            atomicAdd(&hist[r.x >> 7], 1);
            atomicAdd(&hist[r.y >> 7], 1);
            atomicAdd(&hist[r.z >> 7], 1);
            atomicAdd(&hist[r.w >> 7], 1);
        }
    }
    __syncthreads();
    for (int b = tid; b < B2; b += TPB_H) {
        int c = hist[b];
        if (c) atomicAdd(&bcounts[b], c);
    }
}

// ---------------------------------------------------------------------------
// Single-block exclusive scan of the 2344 fine counts -> bstart, bfill, cfill.
__global__ __launch_bounds__(1024) void scan_buckets(
    const int* __restrict__ bcounts, int* __restrict__ bstart,
    int* __restrict__ bfill, int* __restrict__ cfill) {
    __shared__ int lds[1024];
    int t = threadIdx.x;
    int v[4];
    int s = 0;
    #pragma unroll
    for (int k = 0; k < 4; ++k) {
        int b = t * 4 + k;
        v[k] = (b < B2) ? bcounts[b] : 0;
        s += v[k];
    }
    lds[t] = s;
    __syncthreads();
    for (int off = 1; off < 1024; off <<= 1) {
        int u = (t >= off) ? lds[t - off] : 0;
        __syncthreads();
        lds[t] += u;
        __syncthreads();
    }
    int ex = lds[t] - s;                             // exclusive prefix of chunk
    #pragma unroll
    for (int k = 0; k < 4; ++k) {
        int b = t * 4 + k;
        if (b < B2) {
            bstart[b] = ex;
            bfill[b] = ex;
            if ((b & (FPC - 1)) == 0) cfill[b >> 5] = ex;
        }
        ex += v[k];
    }
    if (t == 1023) bstart[B2] = ex;                  // == NE
}

// ---------------------------------------------------------------------------
// Pass A1: coarse partition (74 buckets of 4096 rows), LDS-staged,
// position-major coalesced flush (runs avg 221 edges = 1.77KB).
__global__ __launch_bounds__(TPB_A) void partition_coarse(
    const int4* __restrict__ rows4, const int4* __restrict__ cols4,
    const float4* __restrict__ vals4, int* __restrict__ cfill,
    int2* __restrict__ temp1) {
    __shared__ int2 stage[EPB_A];                    // 128 KB
    __shared__ int hist[NC];
    __shared__ int bnd[NC + 1];
    __shared__ int dlt[NC];
    __shared__ int sc[128];
    int tid = threadIdx.x;
    if (tid < NC) hist[tid] = 0;
    __syncthreads();

    int base4 = blockIdx.x * (EPB_A / 4);
    int keys[EPT]; int vls[EPT]; int crk[EPT];       // crk: coarse<<13|rank

    #pragma unroll
    for (int k = 0; k < EPT / 4; ++k) {
        int i4 = base4 + k * TPB_A + tid;
        if (i4 < NE / 4) {
            int4 r = rows4[i4];
            int4 c = cols4[i4];
            float4 v = vals4[i4];
            int c0 = r.x >> CSH, c1 = r.y >> CSH, c2 = r.z >> CSH, c3 = r.w >> CSH;
            keys[k*4+0] = ((r.x & 4095) << 19) | c.x; vls[k*4+0] = __float_as_int(v.x);
            crk[k*4+0] = (c0 << 13) | atomicAdd(&hist[c0], 1);
            keys[k*4+1] = ((r.y & 4095) << 19) | c.y; vls[k*4+1] = __float_as_int(v.y);
            crk[k*4+1] = (c1 << 13) | atomicAdd(&hist[c1], 1);
            keys[k*4+2] = ((r.z & 4095) << 19) | c.z; vls[k*4+2] = __float_as_int(v.z);
            crk[k*4+2] = (c2 << 13) | atomicAdd(&hist[c2], 1);
            keys[k*4+3] = ((r.w & 4095) << 19) | c.w; vls[k*4+3] = __float_as_int(v.w);
            crk[k*4+3] = (c3 << 13) | atomicAdd(&hist[c3], 1);
        }
    }
    __syncthreads();
    if (tid < 128) sc[tid] = (tid < NC) ? hist[tid] : 0;
    __syncthreads();
    #pragma unroll
    for (int off = 1; off < 128; off <<= 1) {
        int u = (tid >= off && tid < 128) ? sc[tid - off] : 0;
        __syncthreads();
        if (tid < 128) sc[tid] += u;
        __syncthreads();
    }
    if (tid < NC) {
        int cnt = hist[tid];
        int ex = sc[tid] - cnt;
        bnd[tid] = ex;
        dlt[tid] = (cnt ? atomicAdd(&cfill[tid], cnt) : 0) - ex;
    }
    if (tid == 0) bnd[NC] = sc[NC - 1];
    __syncthreads();
    #pragma unroll
    for (int k = 0; k < EPT / 4; ++k) {
        int i4 = base4 + k * TPB_A + tid;
        if (i4 < NE / 4) {
            #pragma unroll
            for (int j = 0; j < 4; ++j) {
                int e = k * 4 + j;
                int p = bnd[crk[e] >> 13] + (crk[e] & 0x1FFF);
                stage[p] = make_int2(keys[e], vls[e]);
            }
        }
    }
    __syncthreads();
    int ntot = bnd[NC];
    for (int j = tid; j < ntot; j += TPB_A) {
        int lo = 0, hi = NC;
        while (hi - lo > 1) { int mid = (lo + hi) >> 1; if (bnd[mid] <= j) lo = mid; else hi = mid; }
        temp1[j + dlt[lo]] = stage[j];
    }
}

// ---------------------------------------------------------------------------
// Pass A2: fine partition within each coarse region (32 fine buckets).
// Output colval is bucket-grouped only — spmm no longer needs a row sort.
__global__ __launch_bounds__(TPB_A) void partition_fine(
    const int2* __restrict__ temp1, const int* __restrict__ bstart,
    int* __restrict__ bfill, int2* __restrict__ colval) {
    __shared__ int2 stage[EPB_A];                    // 128 KB
    __shared__ int hist[FPC];
    __shared__ int bnd[FPC + 1];
    __shared__ int dlt[FPC];
    __shared__ int sc[FPC];
    int c = blockIdx.x / BPC;
    int seg = blockIdx.x % BPC;
    int cs = bstart[c * FPC];
    int ce = bstart[min((c + 1) * FPC, B2)];
    int base = cs + seg * EPB_A;
    int n = ce - base;
    if (n <= 0) return;                              // uniform per block
    if (n > EPB_A) n = EPB_A;
    int tid = threadIdx.x;
    if (tid < FPC) hist[tid] = 0;
    __syncthreads();
    int keys[EPT]; int vls[EPT]; int frk[EPT];       // frk: fine<<13|rank
    #pragma unroll
    for (int k = 0; k < EPT; ++k) {
        int idx = k * TPB_A + tid;
        if (idx < n) {
            int2 e = temp1[base + idx];
            int f = (e.x >> 26) & 31;                // bits 7..11 of row
            keys[k] = e.x; vls[k] = e.y;
            frk[k] = (f << 13) | atomicAdd(&hist[f], 1);
        }
    }
    __syncthreads();
    if (tid < FPC) sc[tid] = hist[tid];
    __syncthreads();
    #pragma unroll
    for (int off = 1; off < FPC; off <<= 1) {
        int u = (tid >= off && tid < FPC) ? sc[tid - off] : 0;
        __syncthreads();
        if (tid < FPC) sc[tid] += u;
        __syncthreads();
    }
    if (tid < FPC) {
        int cnt = hist[tid];
        int ex = sc[tid] - cnt;
        bnd[tid] = ex;
        dlt[tid] = (cnt ? atomicAdd(&bfill[c * FPC + tid], cnt) : 0) - ex;
    }
    if (tid == 0) bnd[FPC] = sc[FPC - 1];
    __syncthreads();
    #pragma unroll
    for (int k = 0; k < EPT; ++k) {
        int idx = k * TPB_A + tid;
        if (idx < n) {
            int p = bnd[frk[k] >> 13] + (frk[k] & 0x1FFF);
            int rl = (keys[k] >> 19) & 127;
            stage[p] = make_int2((rl << 19) | (keys[k] & 0x7FFFF), vls[k]);
        }
    }
    __syncthreads();
    for (int j = tid; j < n; j += TPB_A) {
        int lo = 0, hi = FPC;
        while (hi - lo > 1) { int mid = (lo + hi) >> 1; if (bnd[mid] <= j) lo = mid; else hi = mid; }
        colval[j + dlt[lo]] = stage[j];
    }
}

__device__ __forceinline__ float2 h2f(uint32_t u) {
    return __half22float2(*(__half2*)&u);
}

// ---------------------------------------------------------------------------
// Bucket SpMM: one block per fine bucket (128 rows, ~4096 edges). Edges are
// bucket-grouped (NOT row-sorted — the sort pass is deleted); contributions
// accumulate into an LDS fp32 tile via ds_add_f32. Stride-33 padding spreads
// the random-row atomics across banks (stride 32 would be a structural 8-way
// conflict). Lane layout: grp=lane>>3 edge slot, fq=lane&7 feature quad;
// 4 independent colval->gather chains per wave iteration (32 edges).
// LAST fuses the mean: x3 stays fp32 in LDS; read x0h/x1h/x2h slices
// coalesced; write acc fp32 directly (finalize_mean pass deleted).
template <bool LAST>
__global__ __launch_bounds__(256) void spmm_bucket(
    const int* __restrict__ bstart, const int2* __restrict__ colval,
    const __half* __restrict__ xh, __half* __restrict__ yh,
    const uint4* __restrict__ x0, const uint4* __restrict__ x1,
    const uint4* __restrict__ x2, float4* __restrict__ out) {
    __shared__ float ly[RPB2 * LP];                  // 16.9 KB
    int b = blockIdx.x;
    int tid = threadIdx.x;
    int s = bstart[b];
    int e = bstart[b + 1];
    for (int i = tid; i < RPB2 * LP; i += 256) ly[i] = 0.f;
    __syncthreads();
    int lane = tid & 63;
    int w = tid >> 6;                                // wave 0..3
    int grp = lane >> 3;                             // edge slot in pack
    int fq = lane & 7;                               // feature quad
    const int64_t* cv8 = (const int64_t*)colval;
    int npacks = (e - s + 7) >> 3;                   // 8-edge packs
    int base = 0;
    for (; base + 16 <= npacks; base += 16) {        // full iter: 4 packs/wave
        int i0 = s + (base + w * 4) * 8 + grp;
        int j0 = min(i0, e - 1), j1 = min(i0 + 8, e - 1);
        int j2 = min(i0 + 16, e - 1), j3 = min(i0 + 24, e - 1);
        int64_t k0 = __builtin_nontemporal_load(&cv8[j0]);
        int64_t k1 = __builtin_nontemporal_load(&cv8[j1]);
        int64_t k2 = __builtin_nontemporal_load(&cv8[j2]);
        int64_t k3 = __builtin_nontemporal_load(&cv8[j3]);
        uint2 h0 = *(const uint2*)(xh + (size_t)((uint32_t)k0 & 0x7FFFF) * D + fq * 4);
        uint2 h1 = *(const uint2*)(xh + (size_t)((uint32_t)k1 & 0x7FFFF) * D + fq * 4);
        uint2 h2 = *(const uint2*)(xh + (size_t)((uint32_t)k2 & 0x7FFFF) * D + fq * 4);
        uint2 h3 = *(const uint2*)(xh + (size_t)((uint32_t)k3 & 0x7FFFF) * D + fq * 4);
        float v0 = (i0      < e) ? __int_as_float((int)(k0 >> 32)) : 0.f;
        float v1 = (i0 + 8  < e) ? __int_as_float((int)(k1 >> 32)) : 0.f;
        float v2 = (i0 + 16 < e) ? __int_as_float((int)(k2 >> 32)) : 0.f;
        float v3 = (i0 + 24 < e) ? __int_as_float((int)(k3 >> 32)) : 0.f;
        float* d; float2 f;
        d = &ly[(((uint32_t)k0 >> 19) & 127) * LP + fq * 4];
        f = h2f(h0.x); atomicAdd(&d[0], v0 * f.x); atomicAdd(&d[1], v0 * f.y);
        f = h2f(h0.y); atomicAdd(&d[2], v0 * f.x); atomicAdd(&d[3], v0 * f.y);
        d = &ly[(((uint32_t)k1 >> 19) & 127) * LP + fq * 4];
        f = h2f(h1.x); atomicAdd(&d[0], v1 * f.x); atomicAdd(&d[1], v1 * f.y);
        f = h2f(h1.y); atomicAdd(&d[2], v1 * f.x); atomicAdd(&d[3], v1 * f.y);
        d = &ly[(((uint32_t)k2 >> 19) & 127) * LP + fq * 4];
        f = h2f(h2.x); atomicAdd(&d[0], v2 * f.x); atomicAdd(&d[1], v2 * f.y);
        f = h2f(h2.y); atomicAdd(&d[2], v2 * f.x); atomicAdd(&d[3], v2 * f.y);
        d = &ly[(((uint32_t)k3 >> 19) & 127) * LP + fq * 4];
        f = h2f(h3.x); atomicAdd(&d[0], v3 * f.x); atomicAdd(&d[1], v3 * f.y);
        f = h2f(h3.y); atomicAdd(&d[2], v3 * f.x); atomicAdd(&d[3], v3 * f.y);
    }
    {                                                // tail: <16 packs left
        int p = base + w * 4;
        #pragma unroll
        for (int u = 0; u < 4; ++u) {
            if (p + u < npacks) {
                int i0 = s + (p + u) * 8 + grp;
                int j0 = min(i0, e - 1);
                int64_t k0 = __builtin_nontemporal_load(&cv8[j0]);
                uint2 h0 = *(const uint2*)(xh + (size_t)((uint32_t)k0 & 0x7FFFF) * D + fq * 4);
                float v0 = (i0 < e) ? __int_as_float((int)(k0 >> 32)) : 0.f;
                float* d = &ly[(((uint32_t)k0 >> 19) & 127) * LP + fq * 4];
                float2 f;
                f = h2f(h0.x); atomicAdd(&d[0], v0 * f.x); atomicAdd(&d[1], v0 * f.y);
                f = h2f(h0.y); atomicAdd(&d[2], v0 * f.x); atomicAdd(&d[3], v0 * f.y);
            }
        }
    }
    __syncthreads();
    int row0 = b * RPB2;
    int rcount = min(RPB2, NN - row0);
    if (!LAST) {
        for (int i = tid; i < rcount * 8; i += 256) {
            int rl = i >> 3, q = i & 7;
            float* p = &ly[rl * LP + q * 4];
            __half2 h01 = __float22half2_rn(make_float2(p[0], p[1]));
            __half2 h23 = __float22half2_rn(make_float2(p[2], p[3]));
            *(uint2*)(yh + ((size_t)(row0 + rl) * D + q * 4)) =
                make_uint2(*(uint32_t*)&h01, *(uint32_t*)&h23);
        }
    } else {
        for (int i = tid; i < rcount * 4; i += 256) {
            int rl = i >> 2, q = i & 3;              // q: 8-feature group
            int gi = (row0 + rl) * 4 + q;            // uint4 index
            uint4 a = x0[gi], c = x1[gi], d2 = x2[gi];
            float* p = &ly[rl * LP + q * 8];
            float r[8];
            #pragma unroll
            for (int j = 0; j < 4; ++j) {
                float2 fa = h2f(((const uint32_t*)&a)[j]);
                float2 fc = h2f(((const uint32_t*)&c)[j]);
                float2 fd = h2f(((const uint32_t*)&d2)[j]);
                r[2*j]   = (fa.x + fc.x + fd.x + p[2*j])   * 0.25f;
                r[2*j+1] = (fa.y + fc.y + fd.y + p[2*j+1]) * 0.25f;
            }
            size_t o4 = ((size_t)(row0 + rl) * D + q * 8) / 4;
            out[o4]     = make_float4(r[0], r[1], r[2], r[3]);
            out[o4 + 1] = make_float4(r[4], r[5], r[6], r[7]);
        }
    }
}

extern "C" void kernel_launch(void* const* d_in, const int* in_sizes, int n_in,
                              void* d_out, int out_size, void* d_ws, size_t ws_size,
                              hipStream_t stream) {
    const int*   rows   = (const int*)d_in[0];
    const int*   cols   = (const int*)d_in[1];
    const float* vals   = (const float*)d_in[2];
    const float* user_w = (const float*)d_in[3];
    const float* item_w = (const float*)d_in[4];

    float* acc = (float*)d_out;                      // fp32 output

    // ws layout (16B alignment maintained):
    //   [0, 76.8MB): temp1 (A1 out); post-build x0h|x1h|x2h (3 x 19.2MB)
    //   colval (76.8MB) | bcounts[B2] | bstart[B2+1] | bfill[B2] | cfill[NC]
    __half* x0h = (__half*)d_ws;
    __half* x1h = x0h + (size_t)TOTAL;
    __half* x2h = x1h + (size_t)TOTAL;
    int2*  temp1 = (int2*)d_ws;
    int2*  colval = (int2*)((char*)d_ws + 2ull * (size_t)TOTAL * sizeof(float));
    int*   bcounts = (int*)(colval + (size_t)NE);
    int*   bstart = bcounts + B2;                    // B2+1 entries
    int*   bfill = bstart + (B2 + 1);
    int*   cfill = bfill + B2;                       // NC entries

    const int vec_blocks   = (TOTAL / 4 + 255) / 256;   // 9375
    const int partA_blocks = (NE + EPB_A - 1) / EPB_A;  // 586
    const int partF_blocks = NC * BPC;                  // 666

    // Build bucket-grouped edge list (no row sort needed)
    hipMemsetAsync(bcounts, 0, (size_t)B2 * sizeof(int), stream);
    bucket_hist<<<NB_H, TPB_H, 0, stream>>>((const int4*)rows, bcounts);
    scan_buckets<<<1, 1024, 0, stream>>>(bcounts, bstart, bfill, cfill);
    partition_coarse<<<partA_blocks, TPB_A, 0, stream>>>(
        (const int4*)rows, (const int4*)cols, (const float4*)vals, cfill, temp1);
    partition_fine<<<partF_blocks, TPB_A, 0, stream>>>(
        (const int2*)temp1, bstart, bfill, colval);

    // Embeddings (after build: temp1 aliases x0h..x2h)
    init_x0<<<vec_blocks, 256, 0, stream>>>(
        (const float4*)user_w, (const float4*)item_w, (ushort4*)x0h);

    // 3 propagation layers; LAST fuses the 4-term mean into acc
    spmm_bucket<false><<<B2, 256, 0, stream>>>(
        bstart, colval, x0h, x1h, nullptr, nullptr, nullptr, nullptr);
    spmm_bucket<false><<<B2, 256, 0, stream>>>(
        bstart, colval, x1h, x2h, nullptr, nullptr, nullptr, nullptr);
    spmm_bucket<true ><<<B2, 256, 0, stream>>>(
        bstart, colval, x2h, nullptr, (const uint4*)x0h, (const uint4*)x1h,
        (const uint4*)x2h, (float4*)acc);
}

// Round 8
// 809.947 us; speedup vs baseline: 6.5384x; 6.5384x over previous
//
#include <hip/hip_runtime.h>
#include <hip/hip_fp16.h>
#include <stdint.h>

#define NUM_USERS 200000
#define NUM_ITEMS 100000
#define NN (NUM_USERS + NUM_ITEMS)   // 300000
#define D 32
#define NE 9600000
#define TOTAL (NN * D)               // 9,600,000 elements

#define RPB2 128                     // rows per fine bucket
#define B2 ((NN + RPB2 - 1) / RPB2)  // 2344 fine buckets
#define CAP 5120                     // LDS stage capacity in sort (mean 4096, sigma ~64)

#define CSH 12                       // coarse bucket = row >> 12 (4096 rows)
#define NC ((NN + (1 << CSH) - 1) >> CSH)   // 74 coarse buckets
#define FPC 32                       // fine buckets per coarse (4096/128)
#define BPC 9                        // fine-pass blocks per coarse region

#define TPB_A 1024                   // partition block size
#define EPT 16                       // edges per thread in partition
#define EPB_A (TPB_A * EPT)          // 16384 edges per block

#define TPB_H 1024                   // bucket-hist block size
#define EPT_H 32
#define EPB_H (TPB_H * EPT_H)        // 32768 edges per block
#define NB_H ((NE + EPB_H - 1) / EPB_H)  // 293 blocks

// ---------------------------------------------------------------------------
// init: x0h = fp16 copy of concat(user_w, item_w).
__global__ __launch_bounds__(256) void init_x0(
    const float4* __restrict__ user_w, const float4* __restrict__ item_w,
    ushort4* __restrict__ x0h) {
    int i = blockIdx.x * 256 + threadIdx.x;
    const int total4 = TOTAL / 4;
    const int ub4 = (NUM_USERS * D) / 4;
    if (i < total4) {
        float4 v = (i < ub4) ? user_w[i] : item_w[i - ub4];
        ushort4 h;
        h.x = __half_as_ushort(__float2half(v.x));
        h.y = __half_as_ushort(__float2half(v.y));
        h.z = __half_as_ushort(__float2half(v.z));
        h.w = __half_as_ushort(__float2half(v.w));
        x0h[i] = h;
    }
}

// ---------------------------------------------------------------------------
// Fine-bucket degree histogram, LDS-privatized.
__global__ __launch_bounds__(TPB_H) void bucket_hist(
    const int4* __restrict__ rows4, int* __restrict__ bcounts) {
    __shared__ int hist[B2];                         // 9376 B
    int tid = threadIdx.x;
    for (int i = tid; i < B2; i += TPB_H) hist[i] = 0;
    __syncthreads();
    int base4 = blockIdx.x * (EPB_H / 4);
    #pragma unroll
    for (int k = 0; k < EPT_H / 4; ++k) {
        int i4 = base4 + k * TPB_H + tid;
        if (i4 < NE / 4) {
            int4 r = rows4[i4];
            atomicAdd(&hist[r.x >> 7], 1);
            atomicAdd(&hist[r.y >> 7], 1);
            atomicAdd(&hist[r.z >> 7], 1);
            atomicAdd(&hist[r.w >> 7], 1);
        }
    }
    __syncthreads();
    for (int b = tid; b < B2; b += TPB_H) {
        int c = hist[b];
        if (c) atomicAdd(&bcounts[b], c);
    }
}

// ---------------------------------------------------------------------------
// Single-block exclusive scan of the 2344 fine counts -> bstart, bfill, cfill.
__global__ __launch_bounds__(1024) void scan_buckets(
    const int* __restrict__ bcounts, int* __restrict__ bstart,
    int* __restrict__ bfill, int* __restrict__ cfill) {
    __shared__ int lds[1024];
    int t = threadIdx.x;
    int v[4];
    int s = 0;
    #pragma unroll
    for (int k = 0; k < 4; ++k) {
        int b = t * 4 + k;
        v[k] = (b < B2) ? bcounts[b] : 0;
        s += v[k];
    }
    lds[t] = s;
    __syncthreads();
    for (int off = 1; off < 1024; off <<= 1) {
        int u = (t >= off) ? lds[t - off] : 0;
        __syncthreads();
        lds[t] += u;
        __syncthreads();
    }
    int ex = lds[t] - s;                             // exclusive prefix of chunk
    #pragma unroll
    for (int k = 0; k < 4; ++k) {
        int b = t * 4 + k;
        if (b < B2) {
            bstart[b] = ex;
            bfill[b] = ex;
            if ((b & (FPC - 1)) == 0) cfill[b >> 5] = ex;
        }
        ex += v[k];
    }
    if (t == 1023) bstart[B2] = ex;                  // == NE
}

// ---------------------------------------------------------------------------
// Pass A1: coarse partition (74 buckets of 4096 rows), LDS-staged,
// position-major coalesced flush (runs avg 221 edges = 1.77KB).
__global__ __launch_bounds__(TPB_A) void partition_coarse(
    const int4* __restrict__ rows4, const int4* __restrict__ cols4,
    const float4* __restrict__ vals4, int* __restrict__ cfill,
    int2* __restrict__ temp1) {
    __shared__ int2 stage[EPB_A];                    // 128 KB
    __shared__ int hist[NC];
    __shared__ int bnd[NC + 1];
    __shared__ int dlt[NC];
    __shared__ int sc[128];
    int tid = threadIdx.x;
    if (tid < NC) hist[tid] = 0;
    __syncthreads();

    int base4 = blockIdx.x * (EPB_A / 4);
    int keys[EPT]; int vls[EPT]; int crk[EPT];       // crk: coarse<<13|rank

    #pragma unroll
    for (int k = 0; k < EPT / 4; ++k) {
        int i4 = base4 + k * TPB_A + tid;
        if (i4 < NE / 4) {
            int4 r = rows4[i4];
            int4 c = cols4[i4];
            float4 v = vals4[i4];
            int c0 = r.x >> CSH, c1 = r.y >> CSH, c2 = r.z >> CSH, c3 = r.w >> CSH;
            keys[k*4+0] = ((r.x & 4095) << 19) | c.x; vls[k*4+0] = __float_as_int(v.x);
            crk[k*4+0] = (c0 << 13) | atomicAdd(&hist[c0], 1);
            keys[k*4+1] = ((r.y & 4095) << 19) | c.y; vls[k*4+1] = __float_as_int(v.y);
            crk[k*4+1] = (c1 << 13) | atomicAdd(&hist[c1], 1);
            keys[k*4+2] = ((r.z & 4095) << 19) | c.z; vls[k*4+2] = __float_as_int(v.z);
            crk[k*4+2] = (c2 << 13) | atomicAdd(&hist[c2], 1);
            keys[k*4+3] = ((r.w & 4095) << 19) | c.w; vls[k*4+3] = __float_as_int(v.w);
            crk[k*4+3] = (c3 << 13) | atomicAdd(&hist[c3], 1);
        }
    }
    __syncthreads();
    if (tid < 128) sc[tid] = (tid < NC) ? hist[tid] : 0;
    __syncthreads();
    #pragma unroll
    for (int off = 1; off < 128; off <<= 1) {
        int u = (tid >= off && tid < 128) ? sc[tid - off] : 0;
        __syncthreads();
        if (tid < 128) sc[tid] += u;
        __syncthreads();
    }
    if (tid < NC) {
        int cnt = hist[tid];
        int ex = sc[tid] - cnt;
        bnd[tid] = ex;
        dlt[tid] = (cnt ? atomicAdd(&cfill[tid], cnt) : 0) - ex;
    }
    if (tid == 0) bnd[NC] = sc[NC - 1];
    __syncthreads();
    #pragma unroll
    for (int k = 0; k < EPT / 4; ++k) {
        int i4 = base4 + k * TPB_A + tid;
        if (i4 < NE / 4) {
            #pragma unroll
            for (int j = 0; j < 4; ++j) {
                int e = k * 4 + j;
                int p = bnd[crk[e] >> 13] + (crk[e] & 0x1FFF);
                stage[p] = make_int2(keys[e], vls[e]);
            }
        }
    }
    __syncthreads();
    int ntot = bnd[NC];
    for (int j = tid; j < ntot; j += TPB_A) {
        int lo = 0, hi = NC;
        while (hi - lo > 1) { int mid = (lo + hi) >> 1; if (bnd[mid] <= j) lo = mid; else hi = mid; }
        temp1[j + dlt[lo]] = stage[j];
    }
}

// ---------------------------------------------------------------------------
// Pass A2: fine partition within each coarse region (32 fine buckets).
__global__ __launch_bounds__(TPB_A) void partition_fine(
    const int2* __restrict__ temp1, const int* __restrict__ bstart,
    int* __restrict__ bfill, int2* __restrict__ colval) {
    __shared__ int2 stage[EPB_A];                    // 128 KB
    __shared__ int hist[FPC];
    __shared__ int bnd[FPC + 1];
    __shared__ int dlt[FPC];
    __shared__ int sc[FPC];
    int c = blockIdx.x / BPC;
    int seg = blockIdx.x % BPC;
    int cs = bstart[c * FPC];
    int ce = bstart[min((c + 1) * FPC, B2)];
    int base = cs + seg * EPB_A;
    int n = ce - base;
    if (n <= 0) return;                              // uniform per block
    if (n > EPB_A) n = EPB_A;
    int tid = threadIdx.x;
    if (tid < FPC) hist[tid] = 0;
    __syncthreads();
    int keys[EPT]; int vls[EPT]; int frk[EPT];       // frk: fine<<13|rank
    #pragma unroll
    for (int k = 0; k < EPT; ++k) {
        int idx = k * TPB_A + tid;
        if (idx < n) {
            int2 e = temp1[base + idx];
            int f = (e.x >> 26) & 31;                // bits 7..11 of row
            keys[k] = e.x; vls[k] = e.y;
            frk[k] = (f << 13) | atomicAdd(&hist[f], 1);
        }
    }
    __syncthreads();
    if (tid < FPC) sc[tid] = hist[tid];
    __syncthreads();
    #pragma unroll
    for (int off = 1; off < FPC; off <<= 1) {
        int u = (tid >= off && tid < FPC) ? sc[tid - off] : 0;
        __syncthreads();
        if (tid < FPC) sc[tid] += u;
        __syncthreads();
    }
    if (tid < FPC) {
        int cnt = hist[tid];
        int ex = sc[tid] - cnt;
        bnd[tid] = ex;
        dlt[tid] = (cnt ? atomicAdd(&bfill[c * FPC + tid], cnt) : 0) - ex;
    }
    if (tid == 0) bnd[FPC] = sc[FPC - 1];
    __syncthreads();
    #pragma unroll
    for (int k = 0; k < EPT; ++k) {
        int idx = k * TPB_A + tid;
        if (idx < n) {
            int p = bnd[frk[k] >> 13] + (frk[k] & 0x1FFF);
            int rl = (keys[k] >> 19) & 127;
            stage[p] = make_int2((rl << 19) | (keys[k] & 0x7FFFF), vls[k]);
        }
    }
    __syncthreads();
    for (int j = tid; j < n; j += TPB_A) {
        int lo = 0, hi = FPC;
        while (hi - lo > 1) { int mid = (lo + hi) >> 1; if (bnd[mid] <= j) lo = mid; else hi = mid; }
        colval[j + dlt[lo]] = stage[j];
    }
}

// ---------------------------------------------------------------------------
// Pass B: exact within-bucket counting sort, in-place on colval; row_start out.
__global__ __launch_bounds__(256) void sort_bucket2(
    const int* __restrict__ bstart, int* __restrict__ row_start,
    int2* __restrict__ colval, int2* __restrict__ scratch) {
    __shared__ int2 stage[CAP];                      // 40 KB
    __shared__ int lstart[RPB2];
    __shared__ int lfill[RPB2];
    int b = blockIdx.x;
    int row0 = b * RPB2;
    int rcount = NN - row0; if (rcount > RPB2) rcount = RPB2;
    int tid = threadIdx.x;
    int s = bstart[b];
    int count = bstart[b + 1] - s;

    if (tid < RPB2) lfill[tid] = 0;
    __syncthreads();

    for (int i = tid; i < count; i += 256) {
        int rl = colval[s + i].x >> 19;
        atomicAdd(&lfill[rl], 1);
    }
    __syncthreads();

    int val = (tid < RPB2) ? lfill[tid] : 0;
    if (tid < RPB2) lstart[tid] = val;
    __syncthreads();
    for (int off = 1; off < RPB2; off <<= 1) {
        int u = (tid >= off && tid < RPB2) ? lstart[tid - off] : 0;
        __syncthreads();
        if (tid < RPB2) lstart[tid] += u;
        __syncthreads();
    }
    int ex = (tid < RPB2) ? lstart[tid] - val : 0;
    if (tid < RPB2) {
        lstart[tid] = ex;
        lfill[tid] = 0;                              // reset for rank pass
        if (tid < rcount) row_start[row0 + tid] = s + ex;
    }
    if (b == 0 && tid == 0) row_start[NN] = NE;
    __syncthreads();

    if (count <= CAP) {
        for (int i = tid; i < count; i += 256) {
            int2 e = colval[s + i];
            int rl = e.x >> 19;
            int pos = lstart[rl] + atomicAdd(&lfill[rl], 1);
            stage[pos] = make_int2(e.x & 0x7FFFF, e.y);
        }
        __syncthreads();
        for (int i = tid; i < count; i += 256) colval[s + i] = stage[i];
    } else {
        for (int i = tid; i < count; i += 256) scratch[s + i] = colval[s + i];
        __syncthreads();
        for (int i = tid; i < count; i += 256) {
            int2 e = scratch[s + i];
            int rl = e.x >> 19;
            int pos = lstart[rl] + atomicAdd(&lfill[rl], 1);
            colval[s + pos] = make_int2(e.x & 0x7FFFF, e.y);
        }
    }
}

__device__ __forceinline__ float2 h2f(uint32_t u) {
    return __half22float2(*(__half2*)&u);
}

// ---------------------------------------------------------------------------
// Atomic-free SpMM, wide-gather: ONE wave64 per row, 32-edge step with FOUR
// independent colval->gather chains. LAST fuses the 4-term mean: lanes 0-7
// hold the row's 32 features after the butterfly; read x0h/x1h/x2h coalesced
// (uint2 each) and write acc fp32 directly — x3 is never materialized and
// the separate finalize_mean pass is deleted.
template <bool LAST>
__global__ __launch_bounds__(256) void spmm_csr(
    const int* __restrict__ row_start, const int2* __restrict__ colval,
    const __half* __restrict__ xh, __half* __restrict__ yh,
    const uint2* __restrict__ x0u, const uint2* __restrict__ x1u,
    const uint2* __restrict__ x2u, float4* __restrict__ out) {
    int lane = threadIdx.x & 63;
    int grp = lane >> 3;
    int fq = lane & 7;
    int row = (blockIdx.x * 256 + threadIdx.x) >> 6;
    if (row >= NN) return;
    int s = row_start[row];
    int e = row_start[row + 1];
    const int64_t* cv8 = (const int64_t*)colval;
    float a0 = 0.f, a1 = 0.f, a2 = 0.f, a3 = 0.f;
    int i = s;
    for (; i + 32 <= e; i += 32) {                   // full step: 4 chains
        int64_t p0 = __builtin_nontemporal_load(&cv8[i + grp]);
        int64_t p1 = __builtin_nontemporal_load(&cv8[i + 8 + grp]);
        int64_t p2 = __builtin_nontemporal_load(&cv8[i + 16 + grp]);
        int64_t p3 = __builtin_nontemporal_load(&cv8[i + 24 + grp]);
        uint2 h0 = *(const uint2*)(xh + (size_t)(uint32_t)p0 * D + fq * 4);
        uint2 h1 = *(const uint2*)(xh + (size_t)(uint32_t)p1 * D + fq * 4);
        uint2 h2 = *(const uint2*)(xh + (size_t)(uint32_t)p2 * D + fq * 4);
        uint2 h3 = *(const uint2*)(xh + (size_t)(uint32_t)p3 * D + fq * 4);
        float v0 = __int_as_float((int)(p0 >> 32));
        float v1 = __int_as_float((int)(p1 >> 32));
        float v2 = __int_as_float((int)(p2 >> 32));
        float v3 = __int_as_float((int)(p3 >> 32));
        float2 f;
        f = h2f(h0.x); a0 += v0 * f.x; a1 += v0 * f.y;
        f = h2f(h0.y); a2 += v0 * f.x; a3 += v0 * f.y;
        f = h2f(h1.x); a0 += v1 * f.x; a1 += v1 * f.y;
        f = h2f(h1.y); a2 += v1 * f.x; a3 += v1 * f.y;
        f = h2f(h2.x); a0 += v2 * f.x; a1 += v2 * f.y;
        f = h2f(h2.y); a2 += v2 * f.x; a3 += v2 * f.y;
        f = h2f(h3.x); a0 += v3 * f.x; a1 += v3 * f.y;
        f = h2f(h3.y); a2 += v3 * f.x; a3 += v3 * f.y;
    }
    if (i < e) {                                     // masked step: clamp+zero
        int last = e - 1;
        int i0 = i + grp,      c0 = (i0 < e) ? i0 : last;
        int i1 = i + 8 + grp,  c1 = (i1 < e) ? i1 : last;
        int i2 = i + 16 + grp, c2 = (i2 < e) ? i2 : last;
        int i3 = i + 24 + grp, c3 = (i3 < e) ? i3 : last;
        int64_t p0 = __builtin_nontemporal_load(&cv8[c0]);
        int64_t p1 = __builtin_nontemporal_load(&cv8[c1]);
        int64_t p2 = __builtin_nontemporal_load(&cv8[c2]);
        int64_t p3 = __builtin_nontemporal_load(&cv8[c3]);
        uint2 h0 = *(const uint2*)(xh + (size_t)(uint32_t)p0 * D + fq * 4);
        uint2 h1 = *(const uint2*)(xh + (size_t)(uint32_t)p1 * D + fq * 4);
        uint2 h2 = *(const uint2*)(xh + (size_t)(uint32_t)p2 * D + fq * 4);
        uint2 h3 = *(const uint2*)(xh + (size_t)(uint32_t)p3 * D + fq * 4);
        float v0 = (i0 < e) ? __int_as_float((int)(p0 >> 32)) : 0.f;
        float v1 = (i1 < e) ? __int_as_float((int)(p1 >> 32)) : 0.f;
        float v2 = (i2 < e) ? __int_as_float((int)(p2 >> 32)) : 0.f;
        float v3 = (i3 < e) ? __int_as_float((int)(p3 >> 32)) : 0.f;
        float2 f;
        f = h2f(h0.x); a0 += v0 * f.x; a1 += v0 * f.y;
        f = h2f(h0.y); a2 += v0 * f.x; a3 += v0 * f.y;
        f = h2f(h1.x); a0 += v1 * f.x; a1 += v1 * f.y;
        f = h2f(h1.y); a2 += v1 * f.x; a3 += v1 * f.y;
        f = h2f(h2.x); a0 += v2 * f.x; a1 += v2 * f.y;
        f = h2f(h2.y); a2 += v2 * f.x; a3 += v2 * f.y;
        f = h2f(h3.x); a0 += v3 * f.x; a1 += v3 * f.y;
        f = h2f(h3.y); a2 += v3 * f.x; a3 += v3 * f.y;
    }
    #pragma unroll
    for (int m = 8; m <= 32; m <<= 1) {              // butterfly over edge slots
        a0 += __shfl_xor(a0, m, 64);
        a1 += __shfl_xor(a1, m, 64);
        a2 += __shfl_xor(a2, m, 64);
        a3 += __shfl_xor(a3, m, 64);
    }
    if (lane < 8) {                                  // grp==0, fq==lane
        if (!LAST) {
            size_t idx = (size_t)row * D + lane * 4;
            __half2 h01 = __float22half2_rn(make_float2(a0, a1));
            __half2 h23 = __float22half2_rn(make_float2(a2, a3));
            *(uint2*)(yh + idx) = make_uint2(*(uint32_t*)&h01, *(uint32_t*)&h23);
        } else {
            int gi = row * 8 + lane;                 // uint2 index (4 halves)
            uint2 u0 = x0u[gi], u1 = x1u[gi], u2 = x2u[gi];
            float2 f0a = h2f(u0.x), f0b = h2f(u0.y);
            float2 f1a = h2f(u1.x), f1b = h2f(u1.y);
            float2 f2a = h2f(u2.x), f2b = h2f(u2.y);
            out[gi] = make_float4(
                (f0a.x + f1a.x + f2a.x + a0) * 0.25f,
                (f0a.y + f1a.y + f2a.y + a1) * 0.25f,
                (f0b.x + f1b.x + f2b.x + a2) * 0.25f,
                (f0b.y + f1b.y + f2b.y + a3) * 0.25f);
        }
    }
}

extern "C" void kernel_launch(void* const* d_in, const int* in_sizes, int n_in,
                              void* d_out, int out_size, void* d_ws, size_t ws_size,
                              hipStream_t stream) {
    const int*   rows   = (const int*)d_in[0];
    const int*   cols   = (const int*)d_in[1];
    const float* vals   = (const float*)d_in[2];
    const float* user_w = (const float*)d_in[3];
    const float* item_w = (const float*)d_in[4];

    float* acc = (float*)d_out;                      // fp32 output

    // ws layout (16B alignment maintained):
    //   [0, 76.8MB): temp1 (A1 out; sort fallback scratch);
    //                post-build x0h|x1h|x2h (3 x 19.2MB) alias it
    //   colval (76.8MB) | bcounts[B2] | bstart[B2+1] | bfill[B2] | cfill[NC]
    //   | row_start[NN+1]
    __half* x0h = (__half*)d_ws;
    __half* x1h = x0h + (size_t)TOTAL;
    __half* x2h = x1h + (size_t)TOTAL;
    int2*  temp1 = (int2*)d_ws;
    int2*  colval = (int2*)((char*)d_ws + 2ull * (size_t)TOTAL * sizeof(float));
    int*   bcounts = (int*)(colval + (size_t)NE);
    int*   bstart = bcounts + B2;                    // B2+1 entries
    int*   bfill = bstart + (B2 + 1);
    int*   cfill = bfill + B2;                       // NC entries
    int*   row_start = cfill + NC;                   // NN+1 entries

    const int vec_blocks   = (TOTAL / 4 + 255) / 256;   // 9375
    const int partA_blocks = (NE + EPB_A - 1) / EPB_A;  // 586
    const int partF_blocks = NC * BPC;                  // 666
    const int row_blocks   = (NN + 3) / 4;              // 75000 (1 wave64/row)

    // Build exact CSR
    hipMemsetAsync(bcounts, 0, (size_t)B2 * sizeof(int), stream);
    bucket_hist<<<NB_H, TPB_H, 0, stream>>>((const int4*)rows, bcounts);
    scan_buckets<<<1, 1024, 0, stream>>>(bcounts, bstart, bfill, cfill);
    partition_coarse<<<partA_blocks, TPB_A, 0, stream>>>(
        (const int4*)rows, (const int4*)cols, (const float4*)vals, cfill, temp1);
    partition_fine<<<partF_blocks, TPB_A, 0, stream>>>(
        (const int2*)temp1, bstart, bfill, colval);
    sort_bucket2<<<B2, 256, 0, stream>>>(bstart, row_start, colval, temp1);

    // Embeddings (after build: temp1 aliases x0h..x2h)
    init_x0<<<vec_blocks, 256, 0, stream>>>(
        (const float4*)user_w, (const float4*)item_w, (ushort4*)x0h);

    // 3 propagation layers; LAST fuses the 4-term mean into acc
    spmm_csr<false><<<row_blocks, 256, 0, stream>>>(
        row_start, colval, x0h, x1h, nullptr, nullptr, nullptr, nullptr);
    spmm_csr<false><<<row_blocks, 256, 0, stream>>>(
        row_start, colval, x1h, x2h, nullptr, nullptr, nullptr, nullptr);
    spmm_csr<true ><<<row_blocks, 256, 0, stream>>>(
        row_start, colval, x2h, nullptr, (const uint2*)x0h, (const uint2*)x1h,
        (const uint2*)x2h, (float4*)acc);
}